// Round 4
// baseline (141.212 us; speedup 1.0000x reference)
//
#include <hip/hip_runtime.h>
#include <stdint.h>

// iSTFT as a single fused bf16-MFMA GEMM + overlap-add.
//   frames_windowed[m][n] = sum_k X[m][k] * Tb[k][n]
//   X[m=(b,t)][k=2f+c] = transform[b,f,t,c]   (K = 514, padded to 544)
//   Tb[2f+0][n] =  s_f*cos(2*pi*f*n/512)*win[n]/512
//   Tb[2f+1][n] = -s_f*sin(2*pi*f*n/512)*win[n]/512,  s_f = (f==0||f==256)?1:2
// Overlap-add: out[b, c*256+r] = (F[c-1][256+r] + F[c][r]) / (denorm + eps)
// denorm == 1 exactly in the interior (sqrt-hann, 50% overlap); w^2 at edges.
//
// R4: barrier-free K-loop. R3 post-mortem: __syncthreads drains vmcnt(0)
// every K-step, so the double-buffer prefetch never survived the barrier
// (the m97 structural stall). Fix: NO LDS in the GEMM phase at all.
//  - B fragments: b128 loads straight from the packed table (557KB,
//    L2-resident; staging L2-fit data through LDS was pure overhead).
//  - A fragments: 4x float2 per frag direct from input (16-lane coalesced,
//    128B segments; 3 of 4 wn-waves hit L1 on the same lines).
// K-loop has zero barriers / zero cross-wave deps -> compiler emits counted
// vmcnt before first use (never-drain pattern); waves self-schedule.
// LDS = 36KB epilogue buffer only.

#define EPS_F 1.1920928955078125e-07f
#define TWO_PI_OVER_512 1.2271846303085130e-02f

typedef __bf16 bf16x8 __attribute__((ext_vector_type(8)));
typedef float f32x4 __attribute__((ext_vector_type(4)));

__device__ __forceinline__ uint16_t f2bf_bits(float x) {
  return __builtin_bit_cast(uint16_t, (__bf16)x);
}
__device__ __forceinline__ float bf2f_bits(uint16_t u) {
  return (float)__builtin_bit_cast(__bf16, u);
}

// Table: K=544 rows x N=512, bf16, packed per 16B fragment unit:
//   unit u = (k>>3)*512 + n ; byte = u*16 + (k&7)*2
// A lane's B-fragment (8 consecutive k at col n) is one b128 global load.
__global__ void build_table_kernel(const float* __restrict__ win,
                                   uint8_t* __restrict__ tb) {
  const int k = blockIdx.x;   // 0..543
  const int g = k >> 3;
  for (int n = threadIdx.x; n < 512; n += blockDim.x) {
    float v = 0.0f;
    if (k < 514) {
      const int f = k >> 1;
      const float s = (f == 0 || f == 256) ? 1.0f : 2.0f;
      const int a = (f * n) & 511;                 // exact angle reduction
      const float th = (float)a * TWO_PI_OVER_512;
      const float tr = (k & 1) ? -sinf(th) : cosf(th);
      v = s * tr * win[n] * (1.0f / 512.0f);
    }
    *(uint16_t*)(tb + ((g * 512 + n) << 4) + ((k & 7) << 1)) = f2bf_bits(v);
  }
}

// epilogue frame buffer: 512 cols x 32 rows bf16, pitch 72B, swizzled
__device__ __forceinline__ float rd_sf(const uint8_t* sF, int col, int row2) {
  return bf2f_bits(*(const uint16_t*)(
      sF + col * 72 + ((row2 * 2) ^ (((col >> 4) & 3) << 2))));
}

// One block: batch b, 64 consecutive frames [t0, t0+64), full N=512.
// Owns output chunks [t0+1, t0+63] (+ chunk 0 / chunk 4000 at the ends).
// Adjacent blocks overlap by 1 frame (halo) -> OLA is fully block-local.
__global__ __launch_bounds__(512, 4)
void istft_fused_kernel(const float2* __restrict__ in,   // [B*257*4000] (re,im)
                        const float* __restrict__ win,   // [512]
                        const uint8_t* __restrict__ tb,  // packed table
                        float* __restrict__ out) {
  __shared__ __align__(128) uint8_t sF[36864];  // 512 cols x 72B

  const int tid  = threadIdx.x;
  const int lane = tid & 63;
  const int wave = tid >> 6;       // 0..7
  const int wn   = wave & 3;       // N-quarter
  const int wm   = wave >> 2;      // M-half
  const int colbase = wn * 128;
  const int l15 = lane & 15;
  const int g   = lane >> 4;       // k-group within fragment
  const int b  = blockIdx.y;
  const int ib = blockIdx.x;                // 0..63
  const int t0 = (ib == 63) ? 3936 : ib * 63;

  f32x4 acc[2][8];
#pragma unroll
  for (int mi = 0; mi < 2; ++mi)
#pragma unroll
    for (int nj = 0; nj < 8; ++nj)
      acc[mi][nj] = (f32x4){0.0f, 0.0f, 0.0f, 0.0f};

  const long inBase = (long)b * 257 * 4000;  // float2 elements
  const int trow = t0 + wm * 32 + l15;       // mi=0 row; mi=1 adds 16

#pragma unroll 1
  for (int ks = 0; ks < 17; ++ks) {
    const int f0 = ks * 16 + g * 4;   // 4 consecutive f per lane-group
    // ---- A fragments: 2 x (4 float2 loads -> bf16x8) ----
    bf16x8 af[2];
#pragma unroll
    for (int mi = 0; mi < 2; ++mi) {
      const long mrow = inBase + (long)(trow + mi * 16);
      float2 x[4];
#pragma unroll
      for (int p = 0; p < 4; ++p) {
        x[p] = (f0 + p < 257) ? in[mrow + (long)(f0 + p) * 4000]
                              : (float2){0.0f, 0.0f};
      }
      bf16x8 a;
#pragma unroll
      for (int p = 0; p < 4; ++p) {
        a[2 * p]     = (__bf16)x[p].x;   // k = g*8 + 2p   (re)
        a[2 * p + 1] = (__bf16)x[p].y;   // k = g*8 + 2p+1 (im)
      }
      af[mi] = a;
    }
    // ---- B fragments direct from L2-resident table + MFMA ----
    const uint8_t* tks = tb + (((ks * 4 + g) * 512 + colbase + l15) << 4);
#pragma unroll
    for (int nj = 0; nj < 8; ++nj) {
      const bf16x8 bfr = *(const bf16x8*)(tks + (nj << 8));  // nj*16 cols *16B
      acc[0][nj] = __builtin_amdgcn_mfma_f32_16x16x32_bf16(af[0], bfr,
                                                           acc[0][nj], 0, 0, 0);
      acc[1][nj] = __builtin_amdgcn_mfma_f32_16x16x32_bf16(af[1], bfr,
                                                           acc[1][nj], 0, 0, 0);
    }
  }

  // ---- epilogue: two 32-frame passes through the 36KB swizzled buffer ----
  float* outb = out + (long)b * 1024256;
  const float invd = 1.0f / (1.0f + EPS_F);

  // stage group 0 (frames 0..31 = waves wm==0)
  if (wm == 0) {
#pragma unroll
    for (int mi = 0; mi < 2; ++mi)
#pragma unroll
      for (int nj = 0; nj < 8; ++nj) {
        const int col = colbase + nj * 16 + l15;
        const int q4 = mi * 16 + (g << 2);  // D row = (lane>>4)*4 + r
        const int swz = ((col >> 4) & 3) << 2;
        const uint32_t lo = (uint32_t)f2bf_bits(acc[mi][nj][0]) |
                            ((uint32_t)f2bf_bits(acc[mi][nj][1]) << 16);
        const uint32_t hi = (uint32_t)f2bf_bits(acc[mi][nj][2]) |
                            ((uint32_t)f2bf_bits(acc[mi][nj][3]) << 16);
        *(uint32_t*)(sF + col * 72 + ((q4 * 2) ^ swz))       = lo;
        *(uint32_t*)(sF + col * 72 + (((q4 + 2) * 2) ^ swz)) = hi;
      }
  }
  __syncthreads();
  // OLA chunks 1..31 (frames cl-1, cl both in group 0)
#pragma unroll 1
  for (int i = tid; i < 31 * 256; i += 512) {
    const int cl = 1 + (i >> 8);
    const int r  = i & 255;
    const float v0 = rd_sf(sF, 256 + r, cl - 1);
    const float v1 = rd_sf(sF, r, cl);
    outb[(t0 + cl) * 256 + r] = (v0 + v1) * invd;
  }
  if (ib == 0 && tid < 256) {  // chunk 0: only frame 0, n=r, denorm=win[r]^2
    const float w = win[tid];
    outb[tid] = rd_sf(sF, tid, 0) / (w * w + EPS_F);
  }
  // carry frame 31's upper half for the straddling chunk 32
  const float vsave = (tid < 256) ? rd_sf(sF, 256 + tid, 31) : 0.0f;
  __syncthreads();
  // stage group 1 (frames 32..63 = waves wm==1)
  if (wm == 1) {
#pragma unroll
    for (int mi = 0; mi < 2; ++mi)
#pragma unroll
      for (int nj = 0; nj < 8; ++nj) {
        const int col = colbase + nj * 16 + l15;
        const int q4 = mi * 16 + (g << 2);
        const int swz = ((col >> 4) & 3) << 2;
        const uint32_t lo = (uint32_t)f2bf_bits(acc[mi][nj][0]) |
                            ((uint32_t)f2bf_bits(acc[mi][nj][1]) << 16);
        const uint32_t hi = (uint32_t)f2bf_bits(acc[mi][nj][2]) |
                            ((uint32_t)f2bf_bits(acc[mi][nj][3]) << 16);
        *(uint32_t*)(sF + col * 72 + ((q4 * 2) ^ swz))       = lo;
        *(uint32_t*)(sF + col * 72 + (((q4 + 2) * 2) ^ swz)) = hi;
      }
  }
  __syncthreads();
  if (tid < 256)  // chunk 32: frame 31 (saved) + frame 32 (row2=0)
    outb[(t0 + 32) * 256 + tid] = (vsave + rd_sf(sF, tid, 0)) * invd;
  // OLA chunks 33..63 (frames cl-1, cl in group 1; row2 = frame - 32)
#pragma unroll 1
  for (int i = tid; i < 31 * 256; i += 512) {
    const int cl = 33 + (i >> 8);
    const int r  = i & 255;
    const float v0 = rd_sf(sF, 256 + r, cl - 33);
    const float v1 = rd_sf(sF, r, cl - 32);
    outb[(t0 + cl) * 256 + r] = (v0 + v1) * invd;
  }
  if (ib == 63 && tid < 256) {  // chunk 4000: only frame 3999, n=256+r
    const float w = win[256 + tid];
    outb[1024000 + tid] = rd_sf(sF, 256 + tid, 31) / (w * w + EPS_F);
  }
}

extern "C" void kernel_launch(void* const* d_in, const int* in_sizes, int n_in,
                              void* d_out, int out_size, void* d_ws, size_t ws_size,
                              hipStream_t stream) {
  (void)in_sizes; (void)n_in; (void)out_size; (void)ws_size;
  const float2* tr = (const float2*)d_in[0];
  const float* win = (const float*)d_in[1];
  uint8_t* tb = (uint8_t*)d_ws;  // 544*512*2 = 557056 bytes
  build_table_kernel<<<dim3(544), dim3(256), 0, stream>>>(win, tb);
  istft_fused_kernel<<<dim3(64, 16), dim3(512), 0, stream>>>(tr, win, tb,
                                                             (float*)d_out);
}

// Round 5
// 74.521 us; speedup vs baseline: 1.8949x; 1.8949x over previous
//
#include <hip/hip_runtime.h>
#include <stdint.h>

// iSTFT as a single fused bf16-MFMA GEMM + overlap-add.
//   frames_windowed[m][n] = sum_k X[m][k] * Tb[k][n]
//   X[m=(b,t)][k=2f+c] = transform[b,f,t,c]   (K = 514, padded to 544)
//   Tb[2f+0][n] =  s_f*cos(2*pi*f*n/512)*win[n]/512
//   Tb[2f+1][n] = -s_f*sin(2*pi*f*n/512)*win[n]/512,  s_f = (f==0||f==256)?1:2
// Overlap-add: out[b, c*256+r] = (F[c-1][256+r] + F[c][r]) / (denorm + eps)
// denorm == 1 exactly in the interior (sqrt-hann, 50% overlap); w^2 at edges.
//
// R5: R3 structure + counted-vmcnt pipeline (T4). __syncthreads in the K-loop
// forced a full vmcnt(0) drain per step (the m97 structural stall) -> replace
// with raw s_barrier + hand-counted s_waitcnt so staged loads stay in flight
// across barriers. Per step: issue A(ks+2)->regs (2 ops, instruction count
// kept wave-uniform via clamp+select), issue B(ks+1)->global_load_lds dbuf
// (4 ops), then vmcnt(6) retires exactly through B(ks) (in-order semantics),
// raw barrier, compute, ds_write A(ks+1), lgkmcnt(0) + raw barrier.
// vmcnt N: ks<=14 -> 6, ks==15 -> 4 (no A in flight), ks==16 -> 0.

#define EPS_F 1.1920928955078125e-07f
#define TWO_PI_OVER_512 1.2271846303085130e-02f

typedef __bf16 bf16x4 __attribute__((ext_vector_type(4)));
typedef __bf16 bf16x8 __attribute__((ext_vector_type(8)));
typedef float f32x4 __attribute__((ext_vector_type(4)));

__device__ __forceinline__ uint16_t f2bf_bits(float x) {
  return __builtin_bit_cast(uint16_t, (__bf16)x);
}
__device__ __forceinline__ float bf2f_bits(uint16_t u) {
  return (float)__builtin_bit_cast(__bf16, u);
}
// A-tile swizzle: row*80 + ((grp ^ fa(row))<<4), spreads rows 8/16/32 apart
__device__ __forceinline__ int fa_swz(int row) {
  return (row & 3) ^ (((row >> 3) & 1) << 1) ^ ((row >> 4) & 3);
}
#define GLOAD16(srcp, dstp)                                                   \
  __builtin_amdgcn_global_load_lds(                                          \
      (const __attribute__((address_space(1))) uint32_t*)(srcp),             \
      (__attribute__((address_space(3))) uint32_t*)(dstp), 16, 0, 0)

// Table: K=544 rows x N=512, bf16, packed in 16B units for ds_read_b128 frags:
//   unit u = (k>>3)*512 + n ; byte = ((u<<4) ^ ((g&3)<<5)) + (k&7)*2, g=k>>3
// XOR term = LDS bank swizzle, baked into global layout so tile copies are
// verbatim (global_load_lds requires linear dest: both-sides-or-neither).
__global__ void build_table_kernel(const float* __restrict__ win,
                                   uint8_t* __restrict__ tb) {
  const int k = blockIdx.x;   // 0..543
  const int g = k >> 3;
  for (int n = threadIdx.x; n < 512; n += blockDim.x) {
    float v = 0.0f;
    if (k < 514) {
      const int f = k >> 1;
      const float s = (f == 0 || f == 256) ? 1.0f : 2.0f;
      const int a = (f * n) & 511;                 // exact angle reduction
      const float th = (float)a * TWO_PI_OVER_512;
      const float tr = (k & 1) ? -sinf(th) : cosf(th);
      v = s * tr * win[n] * (1.0f / 512.0f);
    }
    const int off = (((g * 512 + n) << 4) ^ ((g & 3) << 5)) + ((k & 7) << 1);
    *(uint16_t*)(tb + off) = f2bf_bits(v);
  }
}

// epilogue frame buffer: 512 cols x 32 rows bf16, pitch 72B, swizzled
__device__ __forceinline__ float rd_sf(const uint8_t* sF, int col, int row2) {
  return bf2f_bits(*(const uint16_t*)(
      sF + col * 72 + ((row2 * 2) ^ (((col >> 4) & 3) << 2))));
}

// One block: batch b, 64 consecutive frames [t0, t0+64), full N=512.
// Owns output chunks [t0+1, t0+63] (+ chunk 0 / chunk 4000 at the ends).
// Adjacent blocks overlap by 1 frame (halo) -> OLA is fully block-local.
__global__ __launch_bounds__(512, 4)
void istft_fused_kernel(const float2* __restrict__ in,   // [B*257*4000] (re,im)
                        const float* __restrict__ win,   // [512]
                        const uint8_t* __restrict__ tb,  // packed table
                        float* __restrict__ out) {
  __shared__ __align__(128) uint8_t smem[75776];
  uint8_t* sA = smem;           // A staging: 2 x (64 rows x 80B)
  uint8_t* sB = smem + 10240;   // B staging: 2 x 32768B
  uint8_t* sF = smem;           // epilogue: 512 cols x 32 rows, pitch 72B

  const int tid  = threadIdx.x;
  const int lane = tid & 63;
  const int wave = tid >> 6;       // 0..7
  const int wn   = wave & 3;       // N-quarter
  const int wm   = wave >> 2;      // M-half
  const int colbase = wn * 128;
  const int b  = blockIdx.y;
  const int ib = blockIdx.x;                // 0..63
  const int t0 = (ib == 63) ? 3936 : ib * 63;

  f32x4 acc[2][8];
#pragma unroll
  for (int mi = 0; mi < 2; ++mi)
#pragma unroll
    for (int nj = 0; nj < 8; ++nj)
      acc[mi][nj] = (f32x4){0.0f, 0.0f, 0.0f, 0.0f};

  const long inBase = (long)b * 257 * 4000;  // float2 elements
  const int awz = ((((wave >> 1) ^ fa_swz(lane)) << 4) | ((wave & 1) << 3));
  const long tcol = inBase + (t0 + lane);

  // ---- prologue: A(0)->regs, B(0)->sB0, A(1)->queue, A(0)->sA0 ----
  float2 aq0, aq1;
  {
    const int f0 = wave * 2;                       // < 257 always
    float2 a00 = in[tcol + (long)f0 * 4000];       // ops 1,2: A(0)
    float2 a01 = in[tcol + (long)(f0 + 1) * 4000];
    const uint8_t* src = tb + wave * 4096 + lane * 16;   // ops 3..6: B(0)
#pragma unroll
    for (int c = 0; c < 4; ++c) GLOAD16(src + c * 1024, sB + wave * 4096 + c * 1024);
    const int f1 = 16 + wave * 2;                  // ops 7,8: A(1)
    aq0 = in[tcol + (long)f1 * 4000];
    aq1 = in[tcol + (long)(f1 + 1) * 4000];
    bf16x4 pack = {(__bf16)a00.x, (__bf16)a00.y, (__bf16)a01.x, (__bf16)a01.y};
    *(bf16x4*)(sA + lane * 80 + awz) = pack;       // auto vmcnt(6) for a00/a01
  }

#pragma unroll 1
  for (int ks = 0; ks < 17; ++ks) {
    const int cur = ks & 1;
    // ---- (1) A(ks+2) -> regs (uniform 2 loads/wave; clamp+select pad) ----
    float2 ax0 = {0.f, 0.f}, ax1 = {0.f, 0.f};
    if (ks < 15) {
      const int f0 = (ks + 2) * 16 + wave * 2;
      const int fc0 = (f0 < 256) ? f0 : 256;
      const int fc1 = (f0 + 1 < 256) ? f0 + 1 : 256;
      ax0 = in[tcol + (long)fc0 * 4000];
      ax1 = in[tcol + (long)fc1 * 4000];
      if (f0 >= 257)     ax0 = (float2){0.f, 0.f};
      if (f0 + 1 >= 257) ax1 = (float2){0.f, 0.f};
    }
    // ---- (2) B(ks+1) -> sB[(ks+1)&1] via global_load_lds ----
    if (ks < 16) {
      const uint8_t* src = tb + (ks + 1) * 32768 + wave * 4096 + lane * 16;
      uint8_t* dst = sB + (cur ^ 1) * 32768 + wave * 4096;
#pragma unroll
      for (int c = 0; c < 4; ++c) GLOAD16(src + c * 1024, dst + c * 1024);
    }
    // ---- (3) counted wait: retire exactly through B(ks); raw barrier ----
    if (ks < 15)
      asm volatile("s_waitcnt vmcnt(6) lgkmcnt(0)" ::: "memory");
    else if (ks == 15)
      asm volatile("s_waitcnt vmcnt(4) lgkmcnt(0)" ::: "memory");
    else
      asm volatile("s_waitcnt vmcnt(0) lgkmcnt(0)" ::: "memory");
    __builtin_amdgcn_s_barrier();
    __builtin_amdgcn_sched_barrier(0);
    // ---- (4) fragments + MFMA (rows wm*32+[0,32), cols wn*128+[0,128)) ----
    {
      const uint8_t* sAc = sA + cur * 5120;
      const uint8_t* sBc = sB + cur * 32768;
      bf16x8 af[2];
#pragma unroll
      for (int mi = 0; mi < 2; ++mi) {
        const int row = wm * 32 + mi * 16 + (lane & 15);
        af[mi] = *(const bf16x8*)(sAc + row * 80 +
                                  (((lane >> 4) ^ fa_swz(row)) << 4));
      }
#pragma unroll
      for (int nj = 0; nj < 8; ++nj) {
        const int n = colbase + nj * 16 + (lane & 15);
        const int g = lane >> 4;
        const bf16x8 bfr =
            *(const bf16x8*)(sBc + ((((g * 512 + n) << 4) ^ (g << 5))));
        acc[0][nj] = __builtin_amdgcn_mfma_f32_16x16x32_bf16(af[0], bfr,
                                                             acc[0][nj], 0, 0, 0);
        acc[1][nj] = __builtin_amdgcn_mfma_f32_16x16x32_bf16(af[1], bfr,
                                                             acc[1][nj], 0, 0, 0);
      }
    }
    // ---- (5) ds_write A(ks+1) (regs already retired by (3) -> no stall) ----
    if (ks < 16) {
      bf16x4 pack = {(__bf16)aq0.x, (__bf16)aq0.y, (__bf16)aq1.x, (__bf16)aq1.y};
      *(bf16x4*)(sA + (cur ^ 1) * 5120 + lane * 80 + awz) = pack;
    }
    aq0 = ax0; aq1 = ax1;  // rotate A queue
    // ---- (6) ds_write visible, then raw barrier (no vmcnt drain!) ----
    asm volatile("s_waitcnt lgkmcnt(0)" ::: "memory");
    __builtin_amdgcn_s_barrier();
    __builtin_amdgcn_sched_barrier(0);
  }

  // ---- epilogue: two 32-frame passes through a 36KB swizzled buffer ----
  float* outb = out + (long)b * 1024256;
  const float invd = 1.0f / (1.0f + EPS_F);

  // stage group 0 (frames 0..31 = waves wm==0)
  if (wm == 0) {
#pragma unroll
    for (int mi = 0; mi < 2; ++mi)
#pragma unroll
      for (int nj = 0; nj < 8; ++nj) {
        const int col = colbase + nj * 16 + (lane & 15);
        const int q4 = mi * 16 + ((lane >> 4) << 2);  // D row=(lane>>4)*4+r
        const int swz = ((col >> 4) & 3) << 2;
        const uint32_t lo = (uint32_t)f2bf_bits(acc[mi][nj][0]) |
                            ((uint32_t)f2bf_bits(acc[mi][nj][1]) << 16);
        const uint32_t hi = (uint32_t)f2bf_bits(acc[mi][nj][2]) |
                            ((uint32_t)f2bf_bits(acc[mi][nj][3]) << 16);
        *(uint32_t*)(sF + col * 72 + ((q4 * 2) ^ swz))       = lo;
        *(uint32_t*)(sF + col * 72 + (((q4 + 2) * 2) ^ swz)) = hi;
      }
  }
  __syncthreads();
  // OLA chunks 1..31 (frames cl-1, cl both in group 0)
#pragma unroll 1
  for (int i = tid; i < 31 * 256; i += 512) {
    const int cl = 1 + (i >> 8);
    const int r  = i & 255;
    const float v0 = rd_sf(sF, 256 + r, cl - 1);
    const float v1 = rd_sf(sF, r, cl);
    outb[(t0 + cl) * 256 + r] = (v0 + v1) * invd;
  }
  if (ib == 0 && tid < 256) {  // chunk 0: only frame 0, n=r, denorm=win[r]^2
    const float w = win[tid];
    outb[tid] = rd_sf(sF, tid, 0) / (w * w + EPS_F);
  }
  // carry frame 31's upper half for the straddling chunk 32
  const float vsave = (tid < 256) ? rd_sf(sF, 256 + tid, 31) : 0.0f;
  __syncthreads();
  // stage group 1 (frames 32..63 = waves wm==1)
  if (wm == 1) {
#pragma unroll
    for (int mi = 0; mi < 2; ++mi)
#pragma unroll
      for (int nj = 0; nj < 8; ++nj) {
        const int col = colbase + nj * 16 + (lane & 15);
        const int q4 = mi * 16 + ((lane >> 4) << 2);
        const int swz = ((col >> 4) & 3) << 2;
        const uint32_t lo = (uint32_t)f2bf_bits(acc[mi][nj][0]) |
                            ((uint32_t)f2bf_bits(acc[mi][nj][1]) << 16);
        const uint32_t hi = (uint32_t)f2bf_bits(acc[mi][nj][2]) |
                            ((uint32_t)f2bf_bits(acc[mi][nj][3]) << 16);
        *(uint32_t*)(sF + col * 72 + ((q4 * 2) ^ swz))       = lo;
        *(uint32_t*)(sF + col * 72 + (((q4 + 2) * 2) ^ swz)) = hi;
      }
  }
  __syncthreads();
  if (tid < 256)  // chunk 32: frame 31 (saved) + frame 32 (row2=0)
    outb[(t0 + 32) * 256 + tid] = (vsave + rd_sf(sF, tid, 0)) * invd;
  // OLA chunks 33..63 (frames cl-1, cl in group 1; row2 = frame - 32)
#pragma unroll 1
  for (int i = tid; i < 31 * 256; i += 512) {
    const int cl = 33 + (i >> 8);
    const int r  = i & 255;
    const float v0 = rd_sf(sF, 256 + r, cl - 33);
    const float v1 = rd_sf(sF, r, cl - 32);
    outb[(t0 + cl) * 256 + r] = (v0 + v1) * invd;
  }
  if (ib == 63 && tid < 256) {  // chunk 4000: only frame 3999, n=256+r
    const float w = win[256 + tid];
    outb[1024000 + tid] = rd_sf(sF, 256 + tid, 31) / (w * w + EPS_F);
  }
}

extern "C" void kernel_launch(void* const* d_in, const int* in_sizes, int n_in,
                              void* d_out, int out_size, void* d_ws, size_t ws_size,
                              hipStream_t stream) {
  (void)in_sizes; (void)n_in; (void)out_size; (void)ws_size;
  const float2* tr = (const float2*)d_in[0];
  const float* win = (const float*)d_in[1];
  uint8_t* tb = (uint8_t*)d_ws;  // 544*512*2 = 557056 bytes
  build_table_kernel<<<dim3(544), dim3(256), 0, stream>>>(win, tb);
  istft_fused_kernel<<<dim3(64, 16), dim3(512), 0, stream>>>(tr, win, tb,
                                                             (float*)d_out);
}